// Round 7
// baseline (829.569 us; speedup 1.0000x reference)
//
#include <hip/hip_runtime.h>
#include <hip/hip_bf16.h>
#include <cstdint>
#include <cstddef>

#define N_NODES 10000
#define N_EDGES 320000
#define N_GRAPHS 64
#define KCHEB 10
#define C_IN 128
#define C_HID 256
#define C_OUTC 128

static inline size_t align_up(size_t v, size_t a){ return (v + a - 1) / a * a; }

typedef __attribute__((ext_vector_type(8))) short short8;
typedef __attribute__((ext_vector_type(4))) float f32x4;

__device__ inline float bf2f(unsigned int bits16){
  union{ unsigned int i; float f; } v; v.i = bits16 << 16; return v.f;
}
__device__ inline unsigned short f2bf_bits(float f){
  __hip_bfloat16 h = __float2bfloat16(f);
  return *reinterpret_cast<unsigned short*>(&h);
}

// ---------------- graph setup kernels ----------------

__global__ void k_deg(const int* __restrict__ src, const int* __restrict__ dst,
                      int* __restrict__ deg, int* __restrict__ indeg){
  int e = blockIdx.x*blockDim.x + threadIdx.x;
  if(e < N_EDGES){
    atomicAdd(&deg[src[e]], 1);
    atomicAdd(&indeg[dst[e]], 1);
  }
}

__global__ void k_dis(const int* __restrict__ deg, float* __restrict__ dis){
  int i = blockIdx.x*blockDim.x + threadIdx.x;
  if(i < N_NODES){
    int d = deg[i];
    dis[i] = d > 0 ? rsqrtf((float)d) : 0.f;
  }
}

__global__ void k_edgew(const int* __restrict__ src, const int* __restrict__ dst,
                        const float* __restrict__ dis, float* __restrict__ w){
  int e = blockIdx.x*blockDim.x + threadIdx.x;
  if(e < N_EDGES){
    w[e] = -dis[src[e]] * dis[dst[e]];
  }
}

__global__ __launch_bounds__(1024) void k_scan(const int* __restrict__ cnt,
                                               int* __restrict__ offs,
                                               int* __restrict__ cursor){
  __shared__ int part[1024];
  const int n = N_NODES;
  const int CH = (n + 1023) / 1024;
  int tid = threadIdx.x;
  int base = tid * CH;
  int s = 0;
  for(int i = 0; i < CH; i++){
    int idx = base + i;
    if(idx < n) s += cnt[idx];
  }
  part[tid] = s;
  __syncthreads();
  for(int off = 1; off < 1024; off <<= 1){
    int v = (tid >= off) ? part[tid - off] : 0;
    __syncthreads();
    part[tid] += v;
    __syncthreads();
  }
  int run = (tid == 0) ? 0 : part[tid - 1];
  for(int i = 0; i < CH; i++){
    int idx = base + i;
    if(idx < n){
      offs[idx] = run;
      cursor[idx] = run;
      run += cnt[idx];
    }
  }
  if(tid == 1023) offs[n] = part[1023];
}

__global__ void k_scatter(const int* __restrict__ src, const int* __restrict__ dst,
                          const float* __restrict__ w, int* __restrict__ cursor,
                          int* __restrict__ csr_s, float* __restrict__ csr_w){
  int e = blockIdx.x*blockDim.x + threadIdx.x;
  if(e < N_EDGES){
    int d = dst[e];
    int p = atomicAdd(&cursor[d], 1);
    csr_s[p] = src[e];
    csr_w[p] = w[e];
  }
}

__global__ __launch_bounds__(128) void k_gbounds(const int* __restrict__ batch,
                                                 int* __restrict__ gstart,
                                                 int* __restrict__ gcnt){
  int g = threadIdx.x;
  if(g <= N_GRAPHS){
    int lo = 0, hi = N_NODES;
    while(lo < hi){
      int mid = (lo + hi) >> 1;
      if(batch[mid] < g) lo = mid + 1; else hi = mid;
    }
    gstart[g] = lo;
  }
  __syncthreads();
  if(g < N_GRAPHS) gcnt[g] = gstart[g + 1] - gstart[g];
}

// ---------------- propagation ----------------
// out[i,:] = alpha * sum_j w_j * bf16gather(Xb[src_j,:]) - (prev ? prev[i,:] : 0)
// Half-wave per node, edge loop unrolled x8 (8 gathers in flight).

__device__ inline void fma8(float* a, uint4 v, float w){
  a[0] += w * bf2f(v.x & 0xffffu); a[1] += w * bf2f(v.x >> 16);
  a[2] += w * bf2f(v.y & 0xffffu); a[3] += w * bf2f(v.y >> 16);
  a[4] += w * bf2f(v.z & 0xffffu); a[5] += w * bf2f(v.z >> 16);
  a[6] += w * bf2f(v.w & 0xffffu); a[7] += w * bf2f(v.w >> 16);
}

__global__ __launch_bounds__(256) void k_prop256(float* __restrict__ out,
                                                 const __hip_bfloat16* __restrict__ Xb,
                                                 const float* __restrict__ prev,
                                                 const int* __restrict__ csr_s,
                                                 const float* __restrict__ csr_w,
                                                 const int* __restrict__ offs,
                                                 float alpha,
                                                 __hip_bfloat16* __restrict__ tx,
                                                 int tx_stride){
  int hl   = threadIdx.x & 31;
  int node = blockIdx.x * 8 + (threadIdx.x >> 5);
  int j0 = offs[node], j1 = offs[node + 1];
  float a[8] = {};
  const __hip_bfloat16* __restrict__ gbase = Xb + hl * 8;
  int j = j0;
  for(; j + 7 < j1; j += 8){
    int   s[8]; float w[8]; uint4 v[8];
#pragma unroll
    for(int i = 0; i < 8; i++){ s[i] = csr_s[j + i]; w[i] = csr_w[j + i]; }
#pragma unroll
    for(int i = 0; i < 8; i++){ v[i] = *(const uint4*)(gbase + (size_t)s[i] * tx_stride); }
#pragma unroll
    for(int i = 0; i < 8; i++){ fma8(a, v[i], w[i]); }
  }
  for(; j + 3 < j1; j += 4){
    int   s[4]; float w[4]; uint4 v[4];
#pragma unroll
    for(int i = 0; i < 4; i++){ s[i] = csr_s[j + i]; w[i] = csr_w[j + i]; }
#pragma unroll
    for(int i = 0; i < 4; i++){ v[i] = *(const uint4*)(gbase + (size_t)s[i] * tx_stride); }
#pragma unroll
    for(int i = 0; i < 4; i++){ fma8(a, v[i], w[i]); }
  }
  for(; j < j1; j++){
    uint4 v0 = *(const uint4*)(gbase + (size_t)csr_s[j] * tx_stride);
    fma8(a, v0, csr_w[j]);
  }
  float r[8];
#pragma unroll
  for(int i = 0; i < 8; i++) r[i] = alpha * a[i];
  size_t off = (size_t)node * 256 + hl * 8;
  if(prev){
    float4 p0 = *(const float4*)(prev + off);
    float4 p1 = *(const float4*)(prev + off + 4);
    r[0] -= p0.x; r[1] -= p0.y; r[2] -= p0.z; r[3] -= p0.w;
    r[4] -= p1.x; r[5] -= p1.y; r[6] -= p1.z; r[7] -= p1.w;
  }
  *(float4*)(out + off)     = make_float4(r[0], r[1], r[2], r[3]);
  *(float4*)(out + off + 4) = make_float4(r[4], r[5], r[6], r[7]);
  uint4 ob;
  ob.x = (unsigned)f2bf_bits(r[0]) | ((unsigned)f2bf_bits(r[1]) << 16);
  ob.y = (unsigned)f2bf_bits(r[2]) | ((unsigned)f2bf_bits(r[3]) << 16);
  ob.z = (unsigned)f2bf_bits(r[4]) | ((unsigned)f2bf_bits(r[5]) << 16);
  ob.w = (unsigned)f2bf_bits(r[6]) | ((unsigned)f2bf_bits(r[7]) << 16);
  *(uint4*)(tx + (size_t)node * tx_stride + hl * 8) = ob;
}

__global__ __launch_bounds__(256) void k_prop128(float* __restrict__ out,
                                                 const __hip_bfloat16* __restrict__ Xb,
                                                 const float* __restrict__ prev,
                                                 const int* __restrict__ csr_s,
                                                 const float* __restrict__ csr_w,
                                                 const int* __restrict__ offs,
                                                 float alpha,
                                                 __hip_bfloat16* __restrict__ tx,
                                                 int tx_stride){
  int hl   = threadIdx.x & 31;
  int node = blockIdx.x * 8 + (threadIdx.x >> 5);
  int j0 = offs[node], j1 = offs[node + 1];
  float a[4] = {};
  const __hip_bfloat16* __restrict__ gbase = Xb + hl * 4;
  int j = j0;
  for(; j + 7 < j1; j += 8){
    int   s[8]; float w[8]; uint2 v[8];
#pragma unroll
    for(int i = 0; i < 8; i++){ s[i] = csr_s[j + i]; w[i] = csr_w[j + i]; }
#pragma unroll
    for(int i = 0; i < 8; i++){ v[i] = *(const uint2*)(gbase + (size_t)s[i] * tx_stride); }
#pragma unroll
    for(int i = 0; i < 8; i++){
      a[0] += w[i] * bf2f(v[i].x & 0xffffu); a[1] += w[i] * bf2f(v[i].x >> 16);
      a[2] += w[i] * bf2f(v[i].y & 0xffffu); a[3] += w[i] * bf2f(v[i].y >> 16);
    }
  }
  for(; j + 3 < j1; j += 4){
    int   s[4]; float w[4]; uint2 v[4];
#pragma unroll
    for(int i = 0; i < 4; i++){ s[i] = csr_s[j + i]; w[i] = csr_w[j + i]; }
#pragma unroll
    for(int i = 0; i < 4; i++){ v[i] = *(const uint2*)(gbase + (size_t)s[i] * tx_stride); }
#pragma unroll
    for(int i = 0; i < 4; i++){
      a[0] += w[i] * bf2f(v[i].x & 0xffffu); a[1] += w[i] * bf2f(v[i].x >> 16);
      a[2] += w[i] * bf2f(v[i].y & 0xffffu); a[3] += w[i] * bf2f(v[i].y >> 16);
    }
  }
  for(; j < j1; j++){
    float w0 = csr_w[j];
    uint2 v0 = *(const uint2*)(gbase + (size_t)csr_s[j] * tx_stride);
    a[0] += w0 * bf2f(v0.x & 0xffffu); a[1] += w0 * bf2f(v0.x >> 16);
    a[2] += w0 * bf2f(v0.y & 0xffffu); a[3] += w0 * bf2f(v0.y >> 16);
  }
  float r0 = alpha * a[0], r1 = alpha * a[1], r2 = alpha * a[2], r3 = alpha * a[3];
  size_t off = (size_t)node * 128 + hl * 4;
  if(prev){
    float4 pv = *(const float4*)(prev + off);
    r0 -= pv.x; r1 -= pv.y; r2 -= pv.z; r3 -= pv.w;
  }
  *(float4*)(out + off) = make_float4(r0, r1, r2, r3);
  uint2 ob;
  ob.x = (unsigned)f2bf_bits(r0) | ((unsigned)f2bf_bits(r1) << 16);
  ob.y = (unsigned)f2bf_bits(r2) | ((unsigned)f2bf_bits(r3) << 16);
  *(uint2*)(tx + (size_t)node * tx_stride + hl * 4) = ob;
}

// fp32 [rows][C] -> bf16 strided slot (layer-1 input only)
template<int C>
__global__ void k_f2bf(const float* __restrict__ X, __hip_bfloat16* __restrict__ tx,
                       int tx_stride){
  int idx = blockIdx.x * blockDim.x + threadIdx.x;
  const int GPR = C / 4;
  if(idx < N_NODES * GPR){
    int r = idx / GPR;
    int c = (idx - r * GPR) * 4;
    float4 v = *(const float4*)(X + (size_t)r * C + c);
    uint2 ob;
    ob.x = (unsigned)f2bf_bits(v.x) | ((unsigned)f2bf_bits(v.y) << 16);
    ob.y = (unsigned)f2bf_bits(v.z) | ((unsigned)f2bf_bits(v.w) << 16);
    *(uint2*)(tx + (size_t)r * tx_stride + c) = ob;
  }
}

// weight transpose + bf16: WT[o][kc] = W[kc][o]
__global__ void k_wt(const float* __restrict__ W, __hip_bfloat16* __restrict__ WT, int Ktot){
  int idx = blockIdx.x * blockDim.x + threadIdx.x;
  if(idx < Ktot * 256){
    int o = idx / Ktot;
    int kc = idx - o * Ktot;
    WT[idx] = __float2bfloat16(W[(size_t)kc * 256 + o]);
  }
}

// ---------------- split-K MFMA GEMM (no atomics) ----------------
// Pk[M][256] = A[M][kb:kb+Kc](bf16) @ BT[256][kb:kb+Kc](bf16)^T
// grid(2, 313): blockIdx.x selects K-half and partial buffer. Tile 32M x 256N.

__global__ __launch_bounds__(256) void k_gemm_sk(const __hip_bfloat16* __restrict__ A,
                                                 const __hip_bfloat16* __restrict__ BT,
                                                 float* __restrict__ P0,
                                                 float* __restrict__ P1,
                                                 int M, int Ktot){
  __shared__ short As[32 * 64];
  __shared__ short Bs[256 * 64];
  int tid = threadIdx.x;
  int lane = tid & 63;
  int wave = tid >> 6;
  int row0 = blockIdx.y * 32;
  int Kc = Ktot >> 1;
  int kb = blockIdx.x * Kc;
  float* __restrict__ P = blockIdx.x ? P1 : P0;
  int l15 = lane & 15;
  int quad = lane >> 4;
  int wn = wave * 64;

  f32x4 acc[2][4] = {};

  for(int k0 = kb; k0 < kb + Kc; k0 += 64){
    {
      int r = tid >> 3, g = tid & 7;
      uint4 v = make_uint4(0u, 0u, 0u, 0u);
      int gr = row0 + r;
      if(gr < M) v = *(const uint4*)(A + (size_t)gr * Ktot + k0 + g * 8);
      *(uint4*)(As + r * 64 + ((g ^ (r & 7)) * 8)) = v;
    }
#pragma unroll
    for(int i = 0; i < 8; i++){
      int e = tid + i * 256;
      int n = e >> 3, g = e & 7;
      uint4 v = *(const uint4*)(BT + (size_t)n * Ktot + k0 + g * 8);
      *(uint4*)(Bs + n * 64 + ((g ^ (n & 7)) * 8)) = v;
    }
    __syncthreads();
#pragma unroll
    for(int kk = 0; kk < 64; kk += 32){
      int g = (kk >> 3) + quad;
      short8 a[2], b[4];
#pragma unroll
      for(int mi = 0; mi < 2; mi++){
        int r = mi * 16 + l15;
        a[mi] = *(const short8*)(As + r * 64 + ((g ^ (r & 7)) * 8));
      }
#pragma unroll
      for(int ni = 0; ni < 4; ni++){
        int n = wn + ni * 16 + l15;
        b[ni] = *(const short8*)(Bs + n * 64 + ((g ^ (n & 7)) * 8));
      }
#pragma unroll
      for(int mi = 0; mi < 2; mi++)
#pragma unroll
        for(int ni = 0; ni < 4; ni++)
          acc[mi][ni] = __builtin_amdgcn_mfma_f32_16x16x32_bf16(a[mi], b[ni], acc[mi][ni], 0, 0, 0);
    }
    __syncthreads();
  }

#pragma unroll
  for(int mi = 0; mi < 2; mi++){
#pragma unroll
    for(int ni = 0; ni < 4; ni++){
      int gcol = wn + ni * 16 + l15;
#pragma unroll
      for(int r = 0; r < 4; r++){
        int grow = row0 + mi * 16 + quad * 4 + r;
        if(grow < M){
          P[(size_t)grow * C_HID + gcol] = acc[mi][ni][r];
        }
      }
    }
  }
}

// sum partials + bias + relu; optional bf16 copy into next layer's Tx0 slot
__global__ void k_bias_act(const float* __restrict__ P0, const float* __restrict__ P1,
                           const float* __restrict__ bias,
                           float* __restrict__ H, __hip_bfloat16* __restrict__ tx2,
                           int tx2_stride){
  int idx = blockIdx.x * blockDim.x + threadIdx.x;
  if(idx < N_NODES * (C_HID / 4)){
    int r = idx >> 6;
    int c = (idx & 63) * 4;
    size_t o = (size_t)r * C_HID + c;
    float4 v0 = *(const float4*)(P0 + o);
    float4 v1 = *(const float4*)(P1 + o);
    float4 b4 = *(const float4*)(bias + c);
    float4 v;
    v.x = fmaxf(v0.x + v1.x + b4.x, 0.f);
    v.y = fmaxf(v0.y + v1.y + b4.y, 0.f);
    v.z = fmaxf(v0.z + v1.z + b4.z, 0.f);
    v.w = fmaxf(v0.w + v1.w + b4.w, 0.f);
    *(float4*)(H + o) = v;
    if(tx2){
      uint2 ob;
      ob.x = (unsigned)f2bf_bits(v.x) | ((unsigned)f2bf_bits(v.y) << 16);
      ob.y = (unsigned)f2bf_bits(v.z) | ((unsigned)f2bf_bits(v.w) << 16);
      *(uint2*)(tx2 + (size_t)r * tx2_stride + c) = ob;
    }
  }
}

// ---------------- pooling + head ----------------

__global__ __launch_bounds__(128) void k_pool(const float* __restrict__ h,
                                              const int* __restrict__ gstart,
                                              const int* __restrict__ gcnt,
                                              float* __restrict__ pooled){
  int g = blockIdx.x;
  int c = blockIdx.y * 128 + threadIdx.x;
  int s = gstart[g], cnt = gcnt[g];
  float acc = 0.f;
  for(int i = 0; i < cnt; i++) acc += h[(size_t)(s + i) * C_HID + c];
  pooled[g * C_HID + c] = acc / fmaxf((float)cnt, 1.f);
}

__global__ __launch_bounds__(128) void k_final(const float* __restrict__ pooled,
                                               const float* __restrict__ Wout,
                                               const float* __restrict__ bout,
                                               float* __restrict__ out){
  int g = blockIdx.x;
  int o = threadIdx.x;
  float acc = bout[o];
  for(int c = 0; c < C_HID; c++) acc += pooled[g * C_HID + c] * Wout[c * C_OUTC + o];
  out[g * C_OUTC + o] = acc;
}

// ---------------- host ----------------

extern "C" void kernel_launch(void* const* d_in, const int* in_sizes, int n_in,
                              void* d_out, int out_size, void* d_ws, size_t ws_size,
                              hipStream_t stream){
  const float* x    = (const float*)d_in[0];
  const float* W0   = (const float*)d_in[1];
  const float* b0   = (const float*)d_in[2];
  const float* W1   = (const float*)d_in[3];
  const float* b1   = (const float*)d_in[4];
  const float* W2   = (const float*)d_in[5];
  const float* b2   = (const float*)d_in[6];
  const float* Wout = (const float*)d_in[7];
  const float* bout = (const float*)d_in[8];
  const int*   ei   = (const int*)d_in[9];
  const int*   batch= (const int*)d_in[10];
  const int* src = ei;
  const int* dst = ei + N_EDGES;
  float* out = (float*)d_out;

  char* p = (char*)d_ws;
  auto alloc = [&](size_t bytes)->char*{ char* r = p; p += align_up(bytes, 256); return r; };

  int*   deg    = (int*)  alloc(N_NODES * 4);
  int*   indeg  = (int*)  alloc(N_NODES * 4);
  int*   offs   = (int*)  alloc((N_NODES + 1) * 4);
  int*   cursor = (int*)  alloc(N_NODES * 4);
  float* dis    = (float*)alloc(N_NODES * 4);
  float* w_e    = (float*)alloc(N_EDGES * 4);
  int*   csr_s  = (int*)  alloc(N_EDGES * 4);
  float* csr_w  = (float*)alloc(N_EDGES * 4);
  int*   gcnt   = (int*)  alloc(N_GRAPHS * 4);
  int*   gstart = (int*)  alloc((N_GRAPHS + 1) * 4);
  float* pooled = (float*)alloc(N_GRAPHS * C_HID * 4);

  __hip_bfloat16* txall = (__hip_bfloat16*)alloc((size_t)N_NODES * (KCHEB * C_HID) * 2);
  __hip_bfloat16* WT0   = (__hip_bfloat16*)alloc((size_t)KCHEB * C_IN  * C_HID * 2);
  __hip_bfloat16* WT1   = (__hip_bfloat16*)alloc((size_t)KCHEB * C_HID * C_HID * 2);
  __hip_bfloat16* WT2   = (__hip_bfloat16*)alloc((size_t)KCHEB * C_HID * C_HID * 2);
  float* s0 = (float*)alloc((size_t)N_NODES * C_HID * 4);
  float* s1 = (float*)alloc((size_t)N_NODES * C_HID * 4);
  float* s2 = (float*)alloc((size_t)N_NODES * C_HID * 4);
  float* Hb = (float*)alloc((size_t)N_NODES * C_HID * 4);
  float* P0 = (float*)alloc((size_t)N_NODES * C_HID * 4);
  float* P1 = (float*)alloc((size_t)N_NODES * C_HID * 4);

  hipMemsetAsync(deg,   0, N_NODES * 4, stream);
  hipMemsetAsync(indeg, 0, N_NODES * 4, stream);

  const int TB = 256;
  int egrid = (N_EDGES + TB - 1) / TB;
  int ngrid = (N_NODES + TB - 1) / TB;

  k_deg<<<egrid, TB, 0, stream>>>(src, dst, deg, indeg);
  k_dis<<<ngrid, TB, 0, stream>>>(deg, dis);
  k_edgew<<<egrid, TB, 0, stream>>>(src, dst, dis, w_e);
  k_scan<<<1, 1024, 0, stream>>>(indeg, offs, cursor);
  k_scatter<<<egrid, TB, 0, stream>>>(src, dst, w_e, cursor, csr_s, csr_w);
  k_gbounds<<<1, 128, 0, stream>>>(batch, gstart, gcnt);

  {
    int n0 = KCHEB * C_IN  * C_HID;
    int n1 = KCHEB * C_HID * C_HID;
    k_wt<<<(n0 + TB - 1) / TB, TB, 0, stream>>>(W0, WT0, KCHEB * C_IN);
    k_wt<<<(n1 + TB - 1) / TB, TB, 0, stream>>>(W1, WT1, KCHEB * C_HID);
    k_wt<<<(n1 + TB - 1) / TB, TB, 0, stream>>>(W2, WT2, KCHEB * C_HID);
  }

  const int K128 = KCHEB * C_IN;   // 1280
  const int K256 = KCHEB * C_HID;  // 2560
  const int ba_grid = (N_NODES * (C_HID / 4) + TB - 1) / TB;

  // ---- layer 1 (Cin=128) ----
  {
    int ng = N_NODES * (C_IN / 4);
    k_f2bf<C_IN><<<(ng + TB - 1) / TB, TB, 0, stream>>>(x, txall, K128);
    k_prop128<<<N_NODES / 8, 256, 0, stream>>>(s0, txall, nullptr, csr_s, csr_w, offs, 1.f,
                                               txall + C_IN, K128);
    const float* T0 = x;
    float* T1 = s0;
    float* rot[3] = {s0, s1, s2};
    for(int k = 2; k < KCHEB; k++){
      float* T2 = rot[(k - 1) % 3];
      k_prop128<<<N_NODES / 8, 256, 0, stream>>>(T2, txall + (size_t)(k - 1) * C_IN, T0,
                                                 csr_s, csr_w, offs, 2.f,
                                                 txall + (size_t)k * C_IN, K128);
      T0 = T1; T1 = T2;
    }
    k_gemm_sk<<<dim3(2, (N_NODES + 31) / 32), 256, 0, stream>>>(txall, WT0, P0, P1,
                                                                N_NODES, K128);
    k_bias_act<<<ba_grid, TB, 0, stream>>>(P0, P1, b0, Hb, txall, K256);
  }

  // ---- layers 2,3 (Cin=256) ----
  for(int layer = 1; layer < 3; layer++){
    const __hip_bfloat16* WT = (layer == 1) ? WT1 : WT2;
    const float* b = (layer == 1) ? b1 : b2;
    k_prop256<<<N_NODES / 8, 256, 0, stream>>>(s0, txall, nullptr, csr_s, csr_w, offs, 1.f,
                                               txall + C_HID, K256);
    const float* T0 = Hb;
    float* T1 = s0;
    float* rot[3] = {s0, s1, s2};
    for(int k = 2; k < KCHEB; k++){
      float* T2 = rot[(k - 1) % 3];
      k_prop256<<<N_NODES / 8, 256, 0, stream>>>(T2, txall + (size_t)(k - 1) * C_HID, T0,
                                                 csr_s, csr_w, offs, 2.f,
                                                 txall + (size_t)k * C_HID, K256);
      T0 = T1; T1 = T2;
    }
    k_gemm_sk<<<dim3(2, (N_NODES + 31) / 32), 256, 0, stream>>>(txall, WT, P0, P1,
                                                                N_NODES, K256);
    __hip_bfloat16* tx2 = (layer == 1) ? txall : nullptr;
    k_bias_act<<<ba_grid, TB, 0, stream>>>(P0, P1, b, Hb, tx2, K256);
  }

  dim3 pgrid(N_GRAPHS, C_HID / 128);
  k_pool<<<pgrid, 128, 0, stream>>>(Hb, gstart, gcnt, pooled);
  k_final<<<N_GRAPHS, C_OUTC, 0, stream>>>(pooled, Wout, bout, out);
}

// Round 8
// 769.801 us; speedup vs baseline: 1.0776x; 1.0776x over previous
//
#include <hip/hip_runtime.h>
#include <hip/hip_bf16.h>
#include <cstdint>
#include <cstddef>

#define N_NODES 10000
#define N_EDGES 320000
#define N_GRAPHS 64
#define KCHEB 10
#define C_IN 128
#define C_HID 256
#define C_OUTC 128
#define POOL_CHUNK 40

static inline size_t align_up(size_t v, size_t a){ return (v + a - 1) / a * a; }

typedef __attribute__((ext_vector_type(8))) short short8;
typedef __attribute__((ext_vector_type(4))) float f32x4;

__device__ inline float bf2f(unsigned int bits16){
  union{ unsigned int i; float f; } v; v.i = bits16 << 16; return v.f;
}
__device__ inline unsigned short f2bf_bits(float f){
  __hip_bfloat16 h = __float2bfloat16(f);
  return *reinterpret_cast<unsigned short*>(&h);
}

// ---------------- graph setup kernels ----------------

__global__ void k_deg(const int* __restrict__ src, const int* __restrict__ dst,
                      int* __restrict__ deg, int* __restrict__ indeg){
  int e = blockIdx.x*blockDim.x + threadIdx.x;
  if(e < N_EDGES){
    atomicAdd(&deg[src[e]], 1);
    atomicAdd(&indeg[dst[e]], 1);
  }
}

__global__ void k_dis(const int* __restrict__ deg, float* __restrict__ dis){
  int i = blockIdx.x*blockDim.x + threadIdx.x;
  if(i < N_NODES){
    int d = deg[i];
    dis[i] = d > 0 ? rsqrtf((float)d) : 0.f;
  }
}

__global__ void k_edgew(const int* __restrict__ src, const int* __restrict__ dst,
                        const float* __restrict__ dis, float* __restrict__ w){
  int e = blockIdx.x*blockDim.x + threadIdx.x;
  if(e < N_EDGES){
    w[e] = -dis[src[e]] * dis[dst[e]];
  }
}

__global__ __launch_bounds__(1024) void k_scan(const int* __restrict__ cnt,
                                               int* __restrict__ offs,
                                               int* __restrict__ cursor){
  __shared__ int part[1024];
  const int n = N_NODES;
  const int CH = (n + 1023) / 1024;
  int tid = threadIdx.x;
  int base = tid * CH;
  int s = 0;
  for(int i = 0; i < CH; i++){
    int idx = base + i;
    if(idx < n) s += cnt[idx];
  }
  part[tid] = s;
  __syncthreads();
  for(int off = 1; off < 1024; off <<= 1){
    int v = (tid >= off) ? part[tid - off] : 0;
    __syncthreads();
    part[tid] += v;
    __syncthreads();
  }
  int run = (tid == 0) ? 0 : part[tid - 1];
  for(int i = 0; i < CH; i++){
    int idx = base + i;
    if(idx < n){
      offs[idx] = run;
      cursor[idx] = run;
      run += cnt[idx];
    }
  }
  if(tid == 1023) offs[n] = part[1023];
}

__global__ void k_scatter(const int* __restrict__ src, const int* __restrict__ dst,
                          const float* __restrict__ w, int* __restrict__ cursor,
                          int* __restrict__ csr_s, float* __restrict__ csr_w){
  int e = blockIdx.x*blockDim.x + threadIdx.x;
  if(e < N_EDGES){
    int d = dst[e];
    int p = atomicAdd(&cursor[d], 1);
    csr_s[p] = src[e];
    csr_w[p] = w[e];
  }
}

__global__ __launch_bounds__(128) void k_gbounds(const int* __restrict__ batch,
                                                 int* __restrict__ gstart,
                                                 int* __restrict__ gcnt){
  int g = threadIdx.x;
  if(g <= N_GRAPHS){
    int lo = 0, hi = N_NODES;
    while(lo < hi){
      int mid = (lo + hi) >> 1;
      if(batch[mid] < g) lo = mid + 1; else hi = mid;
    }
    gstart[g] = lo;
  }
  __syncthreads();
  if(g < N_GRAPHS) gcnt[g] = gstart[g + 1] - gstart[g];
}

// ---------------- propagation ----------------
// out[i,:] = alpha * sum_j w_j * bf16gather(Xb[src_j,:]) - (prev ? prev[i,:] : 0)
// Half-wave per node. Edge indices/weights loaded cooperatively by 8 lanes and
// broadcast via __shfl (1 coalesced load per 8 edges instead of 16 broadcasts).

__device__ inline void fma8(float* a, uint4 v, float w){
  a[0] += w * bf2f(v.x & 0xffffu); a[1] += w * bf2f(v.x >> 16);
  a[2] += w * bf2f(v.y & 0xffffu); a[3] += w * bf2f(v.y >> 16);
  a[4] += w * bf2f(v.z & 0xffffu); a[5] += w * bf2f(v.z >> 16);
  a[6] += w * bf2f(v.w & 0xffffu); a[7] += w * bf2f(v.w >> 16);
}

__global__ __launch_bounds__(256) void k_prop256(float* __restrict__ out,
                                                 const __hip_bfloat16* __restrict__ Xb,
                                                 const float* __restrict__ prev,
                                                 const int* __restrict__ csr_s,
                                                 const float* __restrict__ csr_w,
                                                 const int* __restrict__ offs,
                                                 float alpha,
                                                 __hip_bfloat16* __restrict__ tx,
                                                 int tx_stride){
  int hl   = threadIdx.x & 31;
  int b32  = threadIdx.x & 32;          // half-wave base within wave
  int node = blockIdx.x * 8 + (threadIdx.x >> 5);
  int j0 = offs[node], j1 = offs[node + 1];
  float a[8] = {};
  const __hip_bfloat16* __restrict__ gbase = Xb + hl * 8;
  int j = j0;
  for(; j + 7 < j1; j += 8){
    int   sv = csr_s[j + (hl & 7)];
    float wv = csr_w[j + (hl & 7)];
    uint4 v[8];
#pragma unroll
    for(int i = 0; i < 8; i++){
      int si = __shfl(sv, b32 + i);
      v[i] = *(const uint4*)(gbase + (size_t)si * tx_stride);
    }
#pragma unroll
    for(int i = 0; i < 8; i++){
      float wi = __shfl(wv, b32 + i);
      fma8(a, v[i], wi);
    }
  }
  for(; j < j1; j++){
    uint4 v0 = *(const uint4*)(gbase + (size_t)csr_s[j] * tx_stride);
    fma8(a, v0, csr_w[j]);
  }
  float r[8];
#pragma unroll
  for(int i = 0; i < 8; i++) r[i] = alpha * a[i];
  size_t off = (size_t)node * 256 + hl * 8;
  if(prev){
    float4 p0 = *(const float4*)(prev + off);
    float4 p1 = *(const float4*)(prev + off + 4);
    r[0] -= p0.x; r[1] -= p0.y; r[2] -= p0.z; r[3] -= p0.w;
    r[4] -= p1.x; r[5] -= p1.y; r[6] -= p1.z; r[7] -= p1.w;
  }
  *(float4*)(out + off)     = make_float4(r[0], r[1], r[2], r[3]);
  *(float4*)(out + off + 4) = make_float4(r[4], r[5], r[6], r[7]);
  uint4 ob;
  ob.x = (unsigned)f2bf_bits(r[0]) | ((unsigned)f2bf_bits(r[1]) << 16);
  ob.y = (unsigned)f2bf_bits(r[2]) | ((unsigned)f2bf_bits(r[3]) << 16);
  ob.z = (unsigned)f2bf_bits(r[4]) | ((unsigned)f2bf_bits(r[5]) << 16);
  ob.w = (unsigned)f2bf_bits(r[6]) | ((unsigned)f2bf_bits(r[7]) << 16);
  *(uint4*)(tx + (size_t)node * tx_stride + hl * 8) = ob;
}

__global__ __launch_bounds__(256) void k_prop128(float* __restrict__ out,
                                                 const __hip_bfloat16* __restrict__ Xb,
                                                 const float* __restrict__ prev,
                                                 const int* __restrict__ csr_s,
                                                 const float* __restrict__ csr_w,
                                                 const int* __restrict__ offs,
                                                 float alpha,
                                                 __hip_bfloat16* __restrict__ tx,
                                                 int tx_stride){
  int hl   = threadIdx.x & 31;
  int b32  = threadIdx.x & 32;
  int node = blockIdx.x * 8 + (threadIdx.x >> 5);
  int j0 = offs[node], j1 = offs[node + 1];
  float a[4] = {};
  const __hip_bfloat16* __restrict__ gbase = Xb + hl * 4;
  int j = j0;
  for(; j + 7 < j1; j += 8){
    int   sv = csr_s[j + (hl & 7)];
    float wv = csr_w[j + (hl & 7)];
    uint2 v[8];
#pragma unroll
    for(int i = 0; i < 8; i++){
      int si = __shfl(sv, b32 + i);
      v[i] = *(const uint2*)(gbase + (size_t)si * tx_stride);
    }
#pragma unroll
    for(int i = 0; i < 8; i++){
      float wi = __shfl(wv, b32 + i);
      a[0] += wi * bf2f(v[i].x & 0xffffu); a[1] += wi * bf2f(v[i].x >> 16);
      a[2] += wi * bf2f(v[i].y & 0xffffu); a[3] += wi * bf2f(v[i].y >> 16);
    }
  }
  for(; j < j1; j++){
    float w0 = csr_w[j];
    uint2 v0 = *(const uint2*)(gbase + (size_t)csr_s[j] * tx_stride);
    a[0] += w0 * bf2f(v0.x & 0xffffu); a[1] += w0 * bf2f(v0.x >> 16);
    a[2] += w0 * bf2f(v0.y & 0xffffu); a[3] += w0 * bf2f(v0.y >> 16);
  }
  float r0 = alpha * a[0], r1 = alpha * a[1], r2 = alpha * a[2], r3 = alpha * a[3];
  size_t off = (size_t)node * 128 + hl * 4;
  if(prev){
    float4 pv = *(const float4*)(prev + off);
    r0 -= pv.x; r1 -= pv.y; r2 -= pv.z; r3 -= pv.w;
  }
  *(float4*)(out + off) = make_float4(r0, r1, r2, r3);
  uint2 ob;
  ob.x = (unsigned)f2bf_bits(r0) | ((unsigned)f2bf_bits(r1) << 16);
  ob.y = (unsigned)f2bf_bits(r2) | ((unsigned)f2bf_bits(r3) << 16);
  *(uint2*)(tx + (size_t)node * tx_stride + hl * 4) = ob;
}

// fp32 [rows][C] -> bf16 strided slot (layer-1 input only)
template<int C>
__global__ void k_f2bf(const float* __restrict__ X, __hip_bfloat16* __restrict__ tx,
                       int tx_stride){
  int idx = blockIdx.x * blockDim.x + threadIdx.x;
  const int GPR = C / 4;
  if(idx < N_NODES * GPR){
    int r = idx / GPR;
    int c = (idx - r * GPR) * 4;
    float4 v = *(const float4*)(X + (size_t)r * C + c);
    uint2 ob;
    ob.x = (unsigned)f2bf_bits(v.x) | ((unsigned)f2bf_bits(v.y) << 16);
    ob.y = (unsigned)f2bf_bits(v.z) | ((unsigned)f2bf_bits(v.w) << 16);
    *(uint2*)(tx + (size_t)r * tx_stride + c) = ob;
  }
}

// weight transpose + bf16: WT[o][kc] = W[kc][o]
__global__ void k_wt(const float* __restrict__ W, __hip_bfloat16* __restrict__ WT, int Ktot){
  int idx = blockIdx.x * blockDim.x + threadIdx.x;
  if(idx < Ktot * 256){
    int o = idx / Ktot;
    int kc = idx - o * Ktot;
    WT[idx] = __float2bfloat16(W[(size_t)kc * 256 + o]);
  }
}

// ---------------- split-K MFMA GEMM (no atomics) ----------------
// Pk[M][256] = A[M][kb:kb+Kc](bf16) @ BT[256][kb:kb+Kc](bf16)^T
// grid(2, 313): blockIdx.x selects K-half and partial buffer. Tile 32M x 256N.

__global__ __launch_bounds__(256) void k_gemm_sk(const __hip_bfloat16* __restrict__ A,
                                                 const __hip_bfloat16* __restrict__ BT,
                                                 float* __restrict__ P0,
                                                 float* __restrict__ P1,
                                                 int M, int Ktot){
  __shared__ short As[32 * 64];
  __shared__ short Bs[256 * 64];
  int tid = threadIdx.x;
  int lane = tid & 63;
  int wave = tid >> 6;
  int row0 = blockIdx.y * 32;
  int Kc = Ktot >> 1;
  int kb = blockIdx.x * Kc;
  float* __restrict__ P = blockIdx.x ? P1 : P0;
  int l15 = lane & 15;
  int quad = lane >> 4;
  int wn = wave * 64;

  f32x4 acc[2][4] = {};

  for(int k0 = kb; k0 < kb + Kc; k0 += 64){
    {
      int r = tid >> 3, g = tid & 7;
      uint4 v = make_uint4(0u, 0u, 0u, 0u);
      int gr = row0 + r;
      if(gr < M) v = *(const uint4*)(A + (size_t)gr * Ktot + k0 + g * 8);
      *(uint4*)(As + r * 64 + ((g ^ (r & 7)) * 8)) = v;
    }
#pragma unroll
    for(int i = 0; i < 8; i++){
      int e = tid + i * 256;
      int n = e >> 3, g = e & 7;
      uint4 v = *(const uint4*)(BT + (size_t)n * Ktot + k0 + g * 8);
      *(uint4*)(Bs + n * 64 + ((g ^ (n & 7)) * 8)) = v;
    }
    __syncthreads();
#pragma unroll
    for(int kk = 0; kk < 64; kk += 32){
      int g = (kk >> 3) + quad;
      short8 a[2], b[4];
#pragma unroll
      for(int mi = 0; mi < 2; mi++){
        int r = mi * 16 + l15;
        a[mi] = *(const short8*)(As + r * 64 + ((g ^ (r & 7)) * 8));
      }
#pragma unroll
      for(int ni = 0; ni < 4; ni++){
        int n = wn + ni * 16 + l15;
        b[ni] = *(const short8*)(Bs + n * 64 + ((g ^ (n & 7)) * 8));
      }
#pragma unroll
      for(int mi = 0; mi < 2; mi++)
#pragma unroll
        for(int ni = 0; ni < 4; ni++)
          acc[mi][ni] = __builtin_amdgcn_mfma_f32_16x16x32_bf16(a[mi], b[ni], acc[mi][ni], 0, 0, 0);
    }
    __syncthreads();
  }

#pragma unroll
  for(int mi = 0; mi < 2; mi++){
#pragma unroll
    for(int ni = 0; ni < 4; ni++){
      int gcol = wn + ni * 16 + l15;
#pragma unroll
      for(int r = 0; r < 4; r++){
        int grow = row0 + mi * 16 + quad * 4 + r;
        if(grow < M){
          P[(size_t)grow * C_HID + gcol] = acc[mi][ni][r];
        }
      }
    }
  }
}

// sum partials + bias + relu; optional bf16 copy into next layer's Tx0 slot
__global__ void k_bias_act(const float* __restrict__ P0, const float* __restrict__ P1,
                           const float* __restrict__ bias,
                           float* __restrict__ H, __hip_bfloat16* __restrict__ tx2,
                           int tx2_stride){
  int idx = blockIdx.x * blockDim.x + threadIdx.x;
  if(idx < N_NODES * (C_HID / 4)){
    int r = idx >> 6;
    int c = (idx & 63) * 4;
    size_t o = (size_t)r * C_HID + c;
    float4 v0 = *(const float4*)(P0 + o);
    float4 v1 = *(const float4*)(P1 + o);
    float4 b4 = *(const float4*)(bias + c);
    float4 v;
    v.x = fmaxf(v0.x + v1.x + b4.x, 0.f);
    v.y = fmaxf(v0.y + v1.y + b4.y, 0.f);
    v.z = fmaxf(v0.z + v1.z + b4.z, 0.f);
    v.w = fmaxf(v0.w + v1.w + b4.w, 0.f);
    *(float4*)(H + o) = v;
    if(tx2){
      uint2 ob;
      ob.x = (unsigned)f2bf_bits(v.x) | ((unsigned)f2bf_bits(v.y) << 16);
      ob.y = (unsigned)f2bf_bits(v.z) | ((unsigned)f2bf_bits(v.w) << 16);
      *(uint2*)(tx2 + (size_t)r * tx2_stride + c) = ob;
    }
  }
}

// ---------------- pooling + head ----------------
// Parallel pool: 250 blocks x 40 nodes; per-thread channel accumulator with
// atomic flush only at graph boundaries (batch is sorted).

__global__ __launch_bounds__(256) void k_pool2(const float* __restrict__ h,
                                               const int* __restrict__ batch,
                                               float* __restrict__ gsum){
  int c  = threadIdx.x;
  int n0 = blockIdx.x * POOL_CHUNK;
  int n1 = n0 + POOL_CHUNK;
  if(n1 > N_NODES) n1 = N_NODES;
  if(n0 >= n1) return;
  float acc = 0.f;
  int cur = batch[n0];
  for(int n = n0; n < n1; n++){
    int g = batch[n];
    if(g != cur){
      atomicAdd(&gsum[cur * C_HID + c], acc);
      acc = 0.f;
      cur = g;
    }
    acc += h[(size_t)n * C_HID + c];
  }
  atomicAdd(&gsum[cur * C_HID + c], acc);
}

__global__ __launch_bounds__(128) void k_final(const float* __restrict__ gsum,
                                               const int* __restrict__ gcnt,
                                               const float* __restrict__ Wout,
                                               const float* __restrict__ bout,
                                               float* __restrict__ out){
  int g = blockIdx.x;
  int o = threadIdx.x;
  float inv = 1.f / fmaxf((float)gcnt[g], 1.f);
  float acc = bout[o];
  for(int c = 0; c < C_HID; c++) acc += gsum[g * C_HID + c] * inv * Wout[c * C_OUTC + o];
  out[g * C_OUTC + o] = acc;
}

// ---------------- host ----------------

extern "C" void kernel_launch(void* const* d_in, const int* in_sizes, int n_in,
                              void* d_out, int out_size, void* d_ws, size_t ws_size,
                              hipStream_t stream){
  const float* x    = (const float*)d_in[0];
  const float* W0   = (const float*)d_in[1];
  const float* b0   = (const float*)d_in[2];
  const float* W1   = (const float*)d_in[3];
  const float* b1   = (const float*)d_in[4];
  const float* W2   = (const float*)d_in[5];
  const float* b2   = (const float*)d_in[6];
  const float* Wout = (const float*)d_in[7];
  const float* bout = (const float*)d_in[8];
  const int*   ei   = (const int*)d_in[9];
  const int*   batch= (const int*)d_in[10];
  const int* src = ei;
  const int* dst = ei + N_EDGES;
  float* out = (float*)d_out;

  char* p = (char*)d_ws;
  auto alloc = [&](size_t bytes)->char*{ char* r = p; p += align_up(bytes, 256); return r; };

  int*   deg    = (int*)  alloc(N_NODES * 4);
  int*   indeg  = (int*)  alloc(N_NODES * 4);
  int*   offs   = (int*)  alloc((N_NODES + 1) * 4);
  int*   cursor = (int*)  alloc(N_NODES * 4);
  float* dis    = (float*)alloc(N_NODES * 4);
  float* w_e    = (float*)alloc(N_EDGES * 4);
  int*   csr_s  = (int*)  alloc(N_EDGES * 4);
  float* csr_w  = (float*)alloc(N_EDGES * 4);
  int*   gcnt   = (int*)  alloc(N_GRAPHS * 4);
  int*   gstart = (int*)  alloc((N_GRAPHS + 1) * 4);
  float* gsum   = (float*)alloc(N_GRAPHS * C_HID * 4);

  __hip_bfloat16* txall = (__hip_bfloat16*)alloc((size_t)N_NODES * (KCHEB * C_HID) * 2);
  __hip_bfloat16* WT0   = (__hip_bfloat16*)alloc((size_t)KCHEB * C_IN  * C_HID * 2);
  __hip_bfloat16* WT1   = (__hip_bfloat16*)alloc((size_t)KCHEB * C_HID * C_HID * 2);
  __hip_bfloat16* WT2   = (__hip_bfloat16*)alloc((size_t)KCHEB * C_HID * C_HID * 2);
  float* s0 = (float*)alloc((size_t)N_NODES * C_HID * 4);
  float* s1 = (float*)alloc((size_t)N_NODES * C_HID * 4);
  float* s2 = (float*)alloc((size_t)N_NODES * C_HID * 4);
  float* Hb = (float*)alloc((size_t)N_NODES * C_HID * 4);
  float* P0 = (float*)alloc((size_t)N_NODES * C_HID * 4);
  float* P1 = (float*)alloc((size_t)N_NODES * C_HID * 4);

  hipMemsetAsync(deg,   0, N_NODES * 4, stream);
  hipMemsetAsync(indeg, 0, N_NODES * 4, stream);
  hipMemsetAsync(gsum,  0, N_GRAPHS * C_HID * 4, stream);

  const int TB = 256;
  int egrid = (N_EDGES + TB - 1) / TB;
  int ngrid = (N_NODES + TB - 1) / TB;

  k_deg<<<egrid, TB, 0, stream>>>(src, dst, deg, indeg);
  k_dis<<<ngrid, TB, 0, stream>>>(deg, dis);
  k_edgew<<<egrid, TB, 0, stream>>>(src, dst, dis, w_e);
  k_scan<<<1, 1024, 0, stream>>>(indeg, offs, cursor);
  k_scatter<<<egrid, TB, 0, stream>>>(src, dst, w_e, cursor, csr_s, csr_w);
  k_gbounds<<<1, 128, 0, stream>>>(batch, gstart, gcnt);

  {
    int n0 = KCHEB * C_IN  * C_HID;
    int n1 = KCHEB * C_HID * C_HID;
    k_wt<<<(n0 + TB - 1) / TB, TB, 0, stream>>>(W0, WT0, KCHEB * C_IN);
    k_wt<<<(n1 + TB - 1) / TB, TB, 0, stream>>>(W1, WT1, KCHEB * C_HID);
    k_wt<<<(n1 + TB - 1) / TB, TB, 0, stream>>>(W2, WT2, KCHEB * C_HID);
  }

  const int K128 = KCHEB * C_IN;   // 1280
  const int K256 = KCHEB * C_HID;  // 2560
  const int ba_grid = (N_NODES * (C_HID / 4) + TB - 1) / TB;

  // ---- layer 1 (Cin=128) ----
  {
    int ng = N_NODES * (C_IN / 4);
    k_f2bf<C_IN><<<(ng + TB - 1) / TB, TB, 0, stream>>>(x, txall, K128);
    k_prop128<<<N_NODES / 8, 256, 0, stream>>>(s0, txall, nullptr, csr_s, csr_w, offs, 1.f,
                                               txall + C_IN, K128);
    const float* T0 = x;
    float* T1 = s0;
    float* rot[3] = {s0, s1, s2};
    for(int k = 2; k < KCHEB; k++){
      float* T2 = rot[(k - 1) % 3];
      k_prop128<<<N_NODES / 8, 256, 0, stream>>>(T2, txall + (size_t)(k - 1) * C_IN, T0,
                                                 csr_s, csr_w, offs, 2.f,
                                                 txall + (size_t)k * C_IN, K128);
      T0 = T1; T1 = T2;
    }
    k_gemm_sk<<<dim3(2, (N_NODES + 31) / 32), 256, 0, stream>>>(txall, WT0, P0, P1,
                                                                N_NODES, K128);
    k_bias_act<<<ba_grid, TB, 0, stream>>>(P0, P1, b0, Hb, txall, K256);
  }

  // ---- layers 2,3 (Cin=256) ----
  for(int layer = 1; layer < 3; layer++){
    const __hip_bfloat16* WT = (layer == 1) ? WT1 : WT2;
    const float* b = (layer == 1) ? b1 : b2;
    k_prop256<<<N_NODES / 8, 256, 0, stream>>>(s0, txall, nullptr, csr_s, csr_w, offs, 1.f,
                                               txall + C_HID, K256);
    const float* T0 = Hb;
    float* T1 = s0;
    float* rot[3] = {s0, s1, s2};
    for(int k = 2; k < KCHEB; k++){
      float* T2 = rot[(k - 1) % 3];
      k_prop256<<<N_NODES / 8, 256, 0, stream>>>(T2, txall + (size_t)(k - 1) * C_HID, T0,
                                                 csr_s, csr_w, offs, 2.f,
                                                 txall + (size_t)k * C_HID, K256);
      T0 = T1; T1 = T2;
    }
    k_gemm_sk<<<dim3(2, (N_NODES + 31) / 32), 256, 0, stream>>>(txall, WT, P0, P1,
                                                                N_NODES, K256);
    __hip_bfloat16* tx2 = (layer == 1) ? txall : nullptr;
    k_bias_act<<<ba_grid, TB, 0, stream>>>(P0, P1, b, Hb, tx2, K256);
  }

  k_pool2<<<(N_NODES + POOL_CHUNK - 1) / POOL_CHUNK, 256, 0, stream>>>(Hb, batch, gsum);
  k_final<<<N_GRAPHS, C_OUTC, 0, stream>>>(gsum, gcnt, Wout, bout, out);
}

// Round 9
// 722.893 us; speedup vs baseline: 1.1476x; 1.0649x over previous
//
#include <hip/hip_runtime.h>
#include <hip/hip_bf16.h>
#include <cstdint>
#include <cstddef>

#define N_NODES 10000
#define N_EDGES 320000
#define N_GRAPHS 64
#define KCHEB 10
#define C_IN 128
#define C_HID 256
#define C_OUTC 128
#define POOL_CHUNK 40

static inline size_t align_up(size_t v, size_t a){ return (v + a - 1) / a * a; }

typedef __attribute__((ext_vector_type(8))) short short8;
typedef __attribute__((ext_vector_type(4))) float f32x4;

__device__ inline float bf2f(unsigned int bits16){
  union{ unsigned int i; float f; } v; v.i = bits16 << 16; return v.f;
}
__device__ inline unsigned short f2bf_bits(float f){
  __hip_bfloat16 h = __float2bfloat16(f);
  return *reinterpret_cast<unsigned short*>(&h);
}

// ---------------- graph setup kernels ----------------

__global__ void k_deg(const int* __restrict__ src, const int* __restrict__ dst,
                      int* __restrict__ deg, int* __restrict__ indeg){
  int e = blockIdx.x*blockDim.x + threadIdx.x;
  if(e < N_EDGES){
    atomicAdd(&deg[src[e]], 1);
    atomicAdd(&indeg[dst[e]], 1);
  }
}

__global__ void k_dis(const int* __restrict__ deg, float* __restrict__ dis){
  int i = blockIdx.x*blockDim.x + threadIdx.x;
  if(i < N_NODES){
    int d = deg[i];
    dis[i] = d > 0 ? rsqrtf((float)d) : 0.f;
  }
}

__global__ void k_edgew(const int* __restrict__ src, const int* __restrict__ dst,
                        const float* __restrict__ dis, float* __restrict__ w){
  int e = blockIdx.x*blockDim.x + threadIdx.x;
  if(e < N_EDGES){
    w[e] = -dis[src[e]] * dis[dst[e]];
  }
}

__global__ __launch_bounds__(1024) void k_scan(const int* __restrict__ cnt,
                                               int* __restrict__ offs,
                                               int* __restrict__ cursor){
  __shared__ int part[1024];
  const int n = N_NODES;
  const int CH = (n + 1023) / 1024;
  int tid = threadIdx.x;
  int base = tid * CH;
  int s = 0;
  for(int i = 0; i < CH; i++){
    int idx = base + i;
    if(idx < n) s += cnt[idx];
  }
  part[tid] = s;
  __syncthreads();
  for(int off = 1; off < 1024; off <<= 1){
    int v = (tid >= off) ? part[tid - off] : 0;
    __syncthreads();
    part[tid] += v;
    __syncthreads();
  }
  int run = (tid == 0) ? 0 : part[tid - 1];
  for(int i = 0; i < CH; i++){
    int idx = base + i;
    if(idx < n){
      offs[idx] = run;
      cursor[idx] = run;
      run += cnt[idx];
    }
  }
  if(tid == 1023) offs[n] = part[1023];
}

__global__ void k_scatter(const int* __restrict__ src, const int* __restrict__ dst,
                          const float* __restrict__ w, int* __restrict__ cursor,
                          int* __restrict__ csr_s, float* __restrict__ csr_w){
  int e = blockIdx.x*blockDim.x + threadIdx.x;
  if(e < N_EDGES){
    int d = dst[e];
    int p = atomicAdd(&cursor[d], 1);
    csr_s[p] = src[e];
    csr_w[p] = w[e];
  }
}

__global__ __launch_bounds__(128) void k_gbounds(const int* __restrict__ batch,
                                                 int* __restrict__ gstart,
                                                 int* __restrict__ gcnt){
  int g = threadIdx.x;
  if(g <= N_GRAPHS){
    int lo = 0, hi = N_NODES;
    while(lo < hi){
      int mid = (lo + hi) >> 1;
      if(batch[mid] < g) lo = mid + 1; else hi = mid;
    }
    gstart[g] = lo;
  }
  __syncthreads();
  if(g < N_GRAPHS) gcnt[g] = gstart[g + 1] - gstart[g];
}

// ---------------- propagation (bf16-only state) ----------------
// tx_k[i,:] = bf16( alpha * sum_j w_j * bf16(Xb[src_j,:]) - (Pb ? Pb[i,:] : 0) )
// Half-wave per node; edge meta loaded cooperatively (8 lanes) + shfl broadcast;
// next batch's csr prefetched before current batch's FMAs.

__device__ inline void fma8(float* a, uint4 v, float w){
  a[0] += w * bf2f(v.x & 0xffffu); a[1] += w * bf2f(v.x >> 16);
  a[2] += w * bf2f(v.y & 0xffffu); a[3] += w * bf2f(v.y >> 16);
  a[4] += w * bf2f(v.z & 0xffffu); a[5] += w * bf2f(v.z >> 16);
  a[6] += w * bf2f(v.w & 0xffffu); a[7] += w * bf2f(v.w >> 16);
}

__global__ __launch_bounds__(256) void k_prop256(const __hip_bfloat16* __restrict__ Xb,
                                                 const __hip_bfloat16* __restrict__ Pb,
                                                 __hip_bfloat16* __restrict__ tx,
                                                 const int* __restrict__ csr_s,
                                                 const float* __restrict__ csr_w,
                                                 const int* __restrict__ offs,
                                                 float alpha){
  const int stride = KCHEB * C_HID;
  int hl   = threadIdx.x & 31;
  int b32  = threadIdx.x & 32;
  int node = blockIdx.x * 8 + (threadIdx.x >> 5);
  int j0 = offs[node], j1 = offs[node + 1];
  float a[8] = {};
  const __hip_bfloat16* __restrict__ gbase = Xb + hl * 8;
  int j = j0;
  int sv = 0; float wv = 0.f;
  bool have = (j + 7 < j1);
  if(have){ sv = csr_s[j + (hl & 7)]; wv = csr_w[j + (hl & 7)]; }
  while(have){
    int jn = j + 8;
    bool more = (jn + 7 < j1);
    int sv2 = 0; float wv2 = 0.f;
    if(more){ sv2 = csr_s[jn + (hl & 7)]; wv2 = csr_w[jn + (hl & 7)]; }
    uint4 v[8];
#pragma unroll
    for(int i = 0; i < 8; i++){
      int si = __shfl(sv, b32 + i);
      v[i] = *(const uint4*)(gbase + (size_t)si * stride);
    }
#pragma unroll
    for(int i = 0; i < 8; i++){
      float wi = __shfl(wv, b32 + i);
      fma8(a, v[i], wi);
    }
    sv = sv2; wv = wv2; j = jn; have = more;
  }
  for(; j < j1; j++){
    uint4 v0 = *(const uint4*)(gbase + (size_t)csr_s[j] * stride);
    fma8(a, v0, csr_w[j]);
  }
  float r[8];
#pragma unroll
  for(int i = 0; i < 8; i++) r[i] = alpha * a[i];
  size_t off = (size_t)node * stride + hl * 8;
  if(Pb){
    uint4 pv = *(const uint4*)(Pb + off);
    r[0] -= bf2f(pv.x & 0xffffu); r[1] -= bf2f(pv.x >> 16);
    r[2] -= bf2f(pv.y & 0xffffu); r[3] -= bf2f(pv.y >> 16);
    r[4] -= bf2f(pv.z & 0xffffu); r[5] -= bf2f(pv.z >> 16);
    r[6] -= bf2f(pv.w & 0xffffu); r[7] -= bf2f(pv.w >> 16);
  }
  uint4 ob;
  ob.x = (unsigned)f2bf_bits(r[0]) | ((unsigned)f2bf_bits(r[1]) << 16);
  ob.y = (unsigned)f2bf_bits(r[2]) | ((unsigned)f2bf_bits(r[3]) << 16);
  ob.z = (unsigned)f2bf_bits(r[4]) | ((unsigned)f2bf_bits(r[5]) << 16);
  ob.w = (unsigned)f2bf_bits(r[6]) | ((unsigned)f2bf_bits(r[7]) << 16);
  *(uint4*)(tx + off) = ob;
}

__global__ __launch_bounds__(256) void k_prop128(const __hip_bfloat16* __restrict__ Xb,
                                                 const __hip_bfloat16* __restrict__ Pb,
                                                 __hip_bfloat16* __restrict__ tx,
                                                 const int* __restrict__ csr_s,
                                                 const float* __restrict__ csr_w,
                                                 const int* __restrict__ offs,
                                                 float alpha){
  const int stride = KCHEB * C_IN;
  int hl   = threadIdx.x & 31;
  int b32  = threadIdx.x & 32;
  int node = blockIdx.x * 8 + (threadIdx.x >> 5);
  int j0 = offs[node], j1 = offs[node + 1];
  float a[4] = {};
  const __hip_bfloat16* __restrict__ gbase = Xb + hl * 4;
  int j = j0;
  int sv = 0; float wv = 0.f;
  bool have = (j + 7 < j1);
  if(have){ sv = csr_s[j + (hl & 7)]; wv = csr_w[j + (hl & 7)]; }
  while(have){
    int jn = j + 8;
    bool more = (jn + 7 < j1);
    int sv2 = 0; float wv2 = 0.f;
    if(more){ sv2 = csr_s[jn + (hl & 7)]; wv2 = csr_w[jn + (hl & 7)]; }
    uint2 v[8];
#pragma unroll
    for(int i = 0; i < 8; i++){
      int si = __shfl(sv, b32 + i);
      v[i] = *(const uint2*)(gbase + (size_t)si * stride);
    }
#pragma unroll
    for(int i = 0; i < 8; i++){
      float wi = __shfl(wv, b32 + i);
      a[0] += wi * bf2f(v[i].x & 0xffffu); a[1] += wi * bf2f(v[i].x >> 16);
      a[2] += wi * bf2f(v[i].y & 0xffffu); a[3] += wi * bf2f(v[i].y >> 16);
    }
    sv = sv2; wv = wv2; j = jn; have = more;
  }
  for(; j < j1; j++){
    float w0 = csr_w[j];
    uint2 v0 = *(const uint2*)(gbase + (size_t)csr_s[j] * stride);
    a[0] += w0 * bf2f(v0.x & 0xffffu); a[1] += w0 * bf2f(v0.x >> 16);
    a[2] += w0 * bf2f(v0.y & 0xffffu); a[3] += w0 * bf2f(v0.y >> 16);
  }
  float r0 = alpha * a[0], r1 = alpha * a[1], r2 = alpha * a[2], r3 = alpha * a[3];
  size_t off = (size_t)node * stride + hl * 4;
  if(Pb){
    uint2 pv = *(const uint2*)(Pb + off);
    r0 -= bf2f(pv.x & 0xffffu); r1 -= bf2f(pv.x >> 16);
    r2 -= bf2f(pv.y & 0xffffu); r3 -= bf2f(pv.y >> 16);
  }
  uint2 ob;
  ob.x = (unsigned)f2bf_bits(r0) | ((unsigned)f2bf_bits(r1) << 16);
  ob.y = (unsigned)f2bf_bits(r2) | ((unsigned)f2bf_bits(r3) << 16);
  *(uint2*)(tx + off) = ob;
}

// fp32 [rows][C] -> bf16 strided slot
template<int C>
__global__ void k_f2bf(const float* __restrict__ X, __hip_bfloat16* __restrict__ tx,
                       int tx_stride){
  int idx = blockIdx.x * blockDim.x + threadIdx.x;
  const int GPR = C / 4;
  if(idx < N_NODES * GPR){
    int r = idx / GPR;
    int c = (idx - r * GPR) * 4;
    float4 v = *(const float4*)(X + (size_t)r * C + c);
    uint2 ob;
    ob.x = (unsigned)f2bf_bits(v.x) | ((unsigned)f2bf_bits(v.y) << 16);
    ob.y = (unsigned)f2bf_bits(v.z) | ((unsigned)f2bf_bits(v.w) << 16);
    *(uint2*)(tx + (size_t)r * tx_stride + c) = ob;
  }
}

// weight transpose + bf16: WT[o][kc] = W[kc][o]
__global__ void k_wt(const float* __restrict__ W, __hip_bfloat16* __restrict__ WT, int Ktot){
  int idx = blockIdx.x * blockDim.x + threadIdx.x;
  if(idx < Ktot * 256){
    int o = idx / Ktot;
    int kc = idx - o * Ktot;
    WT[idx] = __float2bfloat16(W[(size_t)kc * 256 + o]);
  }
}

// ---------------- MFMA GEMM, XCD-pinned swizzle ----------------
// H[M][256] = relu( A[M][Ktot](bf16) @ BT[256][Ktot](bf16)^T + bias )
// 64M x 64N tiles; the 4 col-chunks of a row-group sit on ONE XCD
// (xcd = blockIdx & 7) so A is fetched once per XCD. 640 blocks.

__global__ __launch_bounds__(256) void k_gemm_f(const __hip_bfloat16* __restrict__ A,
                                                const __hip_bfloat16* __restrict__ BT,
                                                const float* __restrict__ bias,
                                                float* __restrict__ H,
                                                int M, int Ktot){
  int b = blockIdx.x;
  int xcd = b & 7;
  int l = b >> 3;
  int m = xcd + 8 * (l >> 2);       // row-tile index, stride 8 within an XCD
  int n = l & 3;                    // col-chunk
  if(m * 64 >= M) return;
  int row0 = m * 64, col0 = n * 64;

  __shared__ short As[64 * 64];
  __shared__ short Bs[64 * 64];
  int tid = threadIdx.x;
  int lane = tid & 63;
  int wave = tid >> 6;
  int l15 = lane & 15;
  int quad = lane >> 4;
  int wm = (wave & 1) * 32;
  int wn = (wave >> 1) * 32;

  f32x4 acc[2][2] = {};

  for(int k0 = 0; k0 < Ktot; k0 += 64){
#pragma unroll
    for(int i = 0; i < 2; i++){
      int e = tid + i * 256;
      int r = e >> 3, g = e & 7;
      uint4 v = make_uint4(0u, 0u, 0u, 0u);
      int gr = row0 + r;
      if(gr < M) v = *(const uint4*)(A + (size_t)gr * Ktot + k0 + g * 8);
      *(uint4*)(As + r * 64 + ((g ^ (r & 7)) * 8)) = v;
    }
#pragma unroll
    for(int i = 0; i < 2; i++){
      int e = tid + i * 256;
      int nn = e >> 3, g = e & 7;
      uint4 v = *(const uint4*)(BT + (size_t)(col0 + nn) * Ktot + k0 + g * 8);
      *(uint4*)(Bs + nn * 64 + ((g ^ (nn & 7)) * 8)) = v;
    }
    __syncthreads();
#pragma unroll
    for(int kk = 0; kk < 64; kk += 32){
      int g = (kk >> 3) + quad;
      short8 a[2], bb[2];
#pragma unroll
      for(int mi = 0; mi < 2; mi++){
        int r = wm + mi * 16 + l15;
        a[mi] = *(const short8*)(As + r * 64 + ((g ^ (r & 7)) * 8));
      }
#pragma unroll
      for(int ni = 0; ni < 2; ni++){
        int nn = wn + ni * 16 + l15;
        bb[ni] = *(const short8*)(Bs + nn * 64 + ((g ^ (nn & 7)) * 8));
      }
#pragma unroll
      for(int mi = 0; mi < 2; mi++)
#pragma unroll
        for(int ni = 0; ni < 2; ni++)
          acc[mi][ni] = __builtin_amdgcn_mfma_f32_16x16x32_bf16(a[mi], bb[ni], acc[mi][ni], 0, 0, 0);
    }
    __syncthreads();
  }

#pragma unroll
  for(int mi = 0; mi < 2; mi++){
#pragma unroll
    for(int ni = 0; ni < 2; ni++){
      int gcol = col0 + wn + ni * 16 + l15;
      float bv = bias[gcol];
#pragma unroll
      for(int r = 0; r < 4; r++){
        int grow = row0 + wm + mi * 16 + quad * 4 + r;
        if(grow < M){
          float v = fmaxf(acc[mi][ni][r] + bv, 0.f);
          H[(size_t)grow * C_HID + gcol] = v;
        }
      }
    }
  }
}

// ---------------- pooling + head ----------------

__global__ __launch_bounds__(256) void k_pool2(const float* __restrict__ h,
                                               const int* __restrict__ batch,
                                               float* __restrict__ gsum){
  int c  = threadIdx.x;
  int n0 = blockIdx.x * POOL_CHUNK;
  int n1 = n0 + POOL_CHUNK;
  if(n1 > N_NODES) n1 = N_NODES;
  if(n0 >= n1) return;
  float acc = 0.f;
  int cur = batch[n0];
  for(int n = n0; n < n1; n++){
    int g = batch[n];
    if(g != cur){
      atomicAdd(&gsum[cur * C_HID + c], acc);
      acc = 0.f;
      cur = g;
    }
    acc += h[(size_t)n * C_HID + c];
  }
  atomicAdd(&gsum[cur * C_HID + c], acc);
}

__global__ __launch_bounds__(128) void k_final(const float* __restrict__ gsum,
                                               const int* __restrict__ gcnt,
                                               const float* __restrict__ Wout,
                                               const float* __restrict__ bout,
                                               float* __restrict__ out){
  int g = blockIdx.x;
  int o = threadIdx.x;
  float inv = 1.f / fmaxf((float)gcnt[g], 1.f);
  float acc = bout[o];
  for(int c = 0; c < C_HID; c++) acc += gsum[g * C_HID + c] * inv * Wout[c * C_OUTC + o];
  out[g * C_OUTC + o] = acc;
}

// ---------------- host ----------------

extern "C" void kernel_launch(void* const* d_in, const int* in_sizes, int n_in,
                              void* d_out, int out_size, void* d_ws, size_t ws_size,
                              hipStream_t stream){
  const float* x    = (const float*)d_in[0];
  const float* W0   = (const float*)d_in[1];
  const float* b0   = (const float*)d_in[2];
  const float* W1   = (const float*)d_in[3];
  const float* b1   = (const float*)d_in[4];
  const float* W2   = (const float*)d_in[5];
  const float* b2   = (const float*)d_in[6];
  const float* Wout = (const float*)d_in[7];
  const float* bout = (const float*)d_in[8];
  const int*   ei   = (const int*)d_in[9];
  const int*   batch= (const int*)d_in[10];
  const int* src = ei;
  const int* dst = ei + N_EDGES;
  float* out = (float*)d_out;

  char* p = (char*)d_ws;
  auto alloc = [&](size_t bytes)->char*{ char* r = p; p += align_up(bytes, 256); return r; };

  int*   deg    = (int*)  alloc(N_NODES * 4);
  int*   indeg  = (int*)  alloc(N_NODES * 4);
  int*   offs   = (int*)  alloc((N_NODES + 1) * 4);
  int*   cursor = (int*)  alloc(N_NODES * 4);
  float* dis    = (float*)alloc(N_NODES * 4);
  float* w_e    = (float*)alloc(N_EDGES * 4);
  int*   csr_s  = (int*)  alloc(N_EDGES * 4);
  float* csr_w  = (float*)alloc(N_EDGES * 4);
  int*   gcnt   = (int*)  alloc(N_GRAPHS * 4);
  int*   gstart = (int*)  alloc((N_GRAPHS + 1) * 4);
  float* gsum   = (float*)alloc(N_GRAPHS * C_HID * 4);

  __hip_bfloat16* txall = (__hip_bfloat16*)alloc((size_t)N_NODES * (KCHEB * C_HID) * 2);
  __hip_bfloat16* WT0   = (__hip_bfloat16*)alloc((size_t)KCHEB * C_IN  * C_HID * 2);
  __hip_bfloat16* WT1   = (__hip_bfloat16*)alloc((size_t)KCHEB * C_HID * C_HID * 2);
  __hip_bfloat16* WT2   = (__hip_bfloat16*)alloc((size_t)KCHEB * C_HID * C_HID * 2);
  float* Hb = (float*)alloc((size_t)N_NODES * C_HID * 4);

  hipMemsetAsync(deg,   0, N_NODES * 4, stream);
  hipMemsetAsync(indeg, 0, N_NODES * 4, stream);
  hipMemsetAsync(gsum,  0, N_GRAPHS * C_HID * 4, stream);

  const int TB = 256;
  int egrid = (N_EDGES + TB - 1) / TB;
  int ngrid = (N_NODES + TB - 1) / TB;

  k_deg<<<egrid, TB, 0, stream>>>(src, dst, deg, indeg);
  k_dis<<<ngrid, TB, 0, stream>>>(deg, dis);
  k_edgew<<<egrid, TB, 0, stream>>>(src, dst, dis, w_e);
  k_scan<<<1, 1024, 0, stream>>>(indeg, offs, cursor);
  k_scatter<<<egrid, TB, 0, stream>>>(src, dst, w_e, cursor, csr_s, csr_w);
  k_gbounds<<<1, 128, 0, stream>>>(batch, gstart, gcnt);

  {
    int n0 = KCHEB * C_IN  * C_HID;
    int n1 = KCHEB * C_HID * C_HID;
    k_wt<<<(n0 + TB - 1) / TB, TB, 0, stream>>>(W0, WT0, KCHEB * C_IN);
    k_wt<<<(n1 + TB - 1) / TB, TB, 0, stream>>>(W1, WT1, KCHEB * C_HID);
    k_wt<<<(n1 + TB - 1) / TB, TB, 0, stream>>>(W2, WT2, KCHEB * C_HID);
  }

  const int K128 = KCHEB * C_IN;   // 1280
  const int K256 = KCHEB * C_HID;  // 2560
  const int GEMM_BLOCKS = 640;     // 8 xcd * 4 col * 20 row-groups

  // ---- layer 1 (Cin=128) ----
  {
    int ng = N_NODES * (C_IN / 4);
    k_f2bf<C_IN><<<(ng + TB - 1) / TB, TB, 0, stream>>>(x, txall, K128);
    for(int k = 1; k < KCHEB; k++){
      const __hip_bfloat16* Xb = txall + (size_t)(k - 1) * C_IN;
      const __hip_bfloat16* Pb = (k >= 2) ? txall + (size_t)(k - 2) * C_IN : nullptr;
      __hip_bfloat16* tx = txall + (size_t)k * C_IN;
      k_prop128<<<N_NODES / 8, 256, 0, stream>>>(Xb, Pb, tx, csr_s, csr_w, offs,
                                                 k == 1 ? 1.f : 2.f);
    }
    k_gemm_f<<<GEMM_BLOCKS, 256, 0, stream>>>(txall, WT0, b0, Hb, N_NODES, K128);
    int ng2 = N_NODES * (C_HID / 4);
    k_f2bf<C_HID><<<(ng2 + TB - 1) / TB, TB, 0, stream>>>(Hb, txall, K256);
  }

  // ---- layers 2,3 (Cin=256) ----
  for(int layer = 1; layer < 3; layer++){
    const __hip_bfloat16* WT = (layer == 1) ? WT1 : WT2;
    const float* b = (layer == 1) ? b1 : b2;
    for(int k = 1; k < KCHEB; k++){
      const __hip_bfloat16* Xb = txall + (size_t)(k - 1) * C_HID;
      const __hip_bfloat16* Pb = (k >= 2) ? txall + (size_t)(k - 2) * C_HID : nullptr;
      __hip_bfloat16* tx = txall + (size_t)k * C_HID;
      k_prop256<<<N_NODES / 8, 256, 0, stream>>>(Xb, Pb, tx, csr_s, csr_w, offs,
                                                 k == 1 ? 1.f : 2.f);
    }
    k_gemm_f<<<GEMM_BLOCKS, 256, 0, stream>>>(txall, WT, b, Hb, N_NODES, K256);
    if(layer == 1){
      int ng2 = N_NODES * (C_HID / 4);
      k_f2bf<C_HID><<<(ng2 + TB - 1) / TB, TB, 0, stream>>>(Hb, txall, K256);
    }
  }

  k_pool2<<<(N_NODES + POOL_CHUNK - 1) / POOL_CHUNK, 256, 0, stream>>>(Hb, batch, gsum);
  k_final<<<N_GRAPHS, C_OUTC, 0, stream>>>(gsum, gcnt, Wout, bout, out);
}